// Round 14
// baseline (3537.483 us; speedup 1.0000x reference)
//
#include <hip/hip_runtime.h>
#include <math.h>

// QPLayer: batched primal-dual IPM, Q=0, G=-I (LP). f64 inputs DELIVERED AS F32
// (established round 8). Schur complement S = A diag(s/z) A^T (40x40), solved
// with COMPLETE-DIAGONAL-PIVOTED LDL^T (greedy max pivot; fixed order exploded
// in round 10), fully register-resident.
// ROUND 14: kill the scratch spill. Round 13's separate Lmh[40] array pushed
// the per-lane register arrays to 160 VGPRs -> compiler spilled Lmh to scratch
// (WRITE_SIZE 381 MB/dispatch, ~900-cyc scratch latency, VALUBusy 20%).
// Fix: store each step's multiplier IN the eliminated column of Sreg (classic
// in-place L storage), guarded by a 64-bit elimMask so later rank-1 updates
// skip stored columns (in round 13 those updates were write-only garbage, so
// this is bit-identical math). P4 reads Lm_t back via the same static-index
// cndmask select chain used for the pivot column. Zero extra array registers.
// 3 barriers/iter. One wave per batch element; 1024 waves = 4/CU (structural).

#define NXV   64
#define MEQ   40
#define NITER 25
#define SIGMA_C 0.1
#define FTB_C   0.99
#define SA 65    // LDS row stride for A (doubles)
#define SS 41    // LDS row stride for S staging (doubles)
#define PIV_DROP_REL 1e-12

__global__ __launch_bounds__(64, 1)
void qp_ipm_kernel(const float* __restrict__ puzzles,
                   const float* __restrict__ Af,
                   const float* __restrict__ lzf,
                   const float* __restrict__ uf,
                   float* __restrict__ out)
{
    __shared__ double Ald[MEQ * SA];   // 20,800 B
    __shared__ double Sl[MEQ * SS];    // 13,120 B
    __shared__ double dl[NXV];         //    512 B

    const int tid = threadIdx.x;       // 0..63, one wave
    const int b   = blockIdx.x;
    const int row = (tid < MEQ) ? tid : 0;

    // ---- setup: A (f32->f64) into LDS; b_r = (A @ exp(log_z0))_row ----
    for (int e = tid; e < MEQ * NXV; e += 64)
        Ald[(e >> 6) * SA + (e & 63)] = (double)Af[e];
    const double ez = exp((double)lzf[tid]);
    __syncthreads();
    double b_r = 0.0;
    #pragma unroll 4
    for (int i = 0; i < NXV; ++i) b_r += Ald[row * SA + i] * __shfl(ez, i, 64);

    const double u_i = (double)uf[tid];
    const double p_i = -(double)puzzles[b * NXV + tid];
    double x_r = 0.0, s_r = 1.0, z_r = 1.0, y_r = 0.0;

    for (int it = 0; it < NITER; ++it) {
        // ---- P1: residuals/scalings, registers (uniform flow) ----
        double aty = 0.0;
        #pragma unroll 4
        for (int j = 0; j < MEQ; ++j) aty += Ald[j * SA + tid] * __shfl(y_r, j, 64);
        const double rd = p_i + aty - z_r;          // Q=0, G^T z = -z
        const double rs = s_r - x_r - u_i;          // -x + s - u
        double m = s_r * z_r;
        for (int off = 32; off; off >>= 1) m += __shfl_xor(m, off, 64);
        const double mu = m * (1.0 / 64.0);
        const double rc = (SIGMA_C * mu - z_r * s_r + z_r * rs) / s_r;
        const double rx = rc - rd;                  // rhs_x
        const double d_r = s_r / z_r;
        const double v_r = d_r * rx + x_r;          // fy = A v - b

        double fy_r = 0.0;                          // rhs_y at lane row
        #pragma unroll 4
        for (int i = 0; i < NXV; ++i) fy_r += Ald[row * SA + i] * __shfl(v_r, i, 64);
        fy_r -= b_r;

        dl[tid] = d_r;                              // stage d (all 64 lanes)
        __syncthreads();                            // barrier 0: dl visible

        // ---- P2: S = A diag(d) A^T, 4x4 lower tiles (lanes<55) -> LDS ----
        if (tid < 55) {
            int uu = tid, mb = 0;
            while (uu > mb) { uu -= (mb + 1); ++mb; }
            const int nb = uu;
            double a00=0,a01=0,a02=0,a03=0, a10=0,a11=0,a12=0,a13=0,
                   a20=0,a21=0,a22=0,a23=0, a30=0,a31=0,a32=0,a33=0;
            const double* Am = &Ald[(4 * mb) * SA];
            const double* An = &Ald[(4 * nb) * SA];
            for (int k = 0; k < NXV; ++k) {
                const double dk = dl[k];            // LDS read — uniform source
                const double r0 = Am[0*SA+k], r1 = Am[1*SA+k], r2 = Am[2*SA+k], r3 = Am[3*SA+k];
                const double c0 = An[0*SA+k]*dk, c1 = An[1*SA+k]*dk, c2 = An[2*SA+k]*dk, c3 = An[3*SA+k]*dk;
                a00 += r0*c0; a01 += r0*c1; a02 += r0*c2; a03 += r0*c3;
                a10 += r1*c0; a11 += r1*c1; a12 += r1*c2; a13 += r1*c3;
                a20 += r2*c0; a21 += r2*c1; a22 += r2*c2; a23 += r2*c3;
                a30 += r3*c0; a31 += r3*c1; a32 += r3*c2; a33 += r3*c3;
            }
            double* Sp = &Sl[(4 * mb) * SS + 4 * nb];
            Sp[0*SS+0]=a00; Sp[0*SS+1]=a01; Sp[0*SS+2]=a02; Sp[0*SS+3]=a03;
            Sp[1*SS+0]=a10; Sp[1*SS+1]=a11; Sp[1*SS+2]=a12; Sp[1*SS+3]=a13;
            Sp[2*SS+0]=a20; Sp[2*SS+1]=a21; Sp[2*SS+2]=a22; Sp[2*SS+3]=a23;
            Sp[3*SS+0]=a30; Sp[3*SS+1]=a31; Sp[3*SS+2]=a32; Sp[3*SS+3]=a33;
        }
        __syncthreads();   // barrier 1: tiles visible

        // ---- load row tid of S into registers (symmetric fill) ----
        double Sreg[MEQ];
        double diag_r;
        if (tid < MEQ) {
            #pragma unroll
            for (int j = 0; j < MEQ; ++j)
                Sreg[j] = (j <= tid) ? Sl[tid * SS + j] : Sl[j * SS + tid];
            diag_r = Sl[tid * SS + tid];
        } else {
            #pragma unroll
            for (int j = 0; j < MEQ; ++j) Sreg[j] = 0.0;
            diag_r = -1.0e308;
        }
        double dg = diag_r;
        for (int off = 32; off; off >>= 1) dg = fmax(dg, __shfl_xor(dg, off, 64));
        const double thr = dg * PIV_DROP_REL;
        __syncthreads();   // barrier 2: Sl free for next iteration

        // ---- P3: greedy-max-pivot LDL^T, multipliers stored in-place ----
        unsigned long long elimMask = 0ull;
        double ip_own = 0.0;
        int    kk_own = 0;
        for (int t = 0; t < MEQ; ++t) {
            // argmax over remaining diagonal (selector butterfly)
            double v = diag_r; int idx = tid;
            for (int off = 32; off; off >>= 1) {
                const double ov = __shfl_xor(v, off, 64);
                const int    oi = __shfl_xor(idx, off, 64);
                if (ov > v || (ov == v && oi < idx)) { v = ov; idx = oi; }
            }
            const int kt = __builtin_amdgcn_readfirstlane(idx);
            // col_i = S[i][kt] — static-index cndmask select chain
            double col = Sreg[0];
            #pragma unroll
            for (int j = 1; j < MEQ; ++j) if (j == kt) col = Sreg[j];
            const double piv  = __shfl(col, kt, 64);         // stored-copy pivot
            const double invP = (piv > thr) ? (1.0 / piv) : 0.0;
            if (tid == t) { kk_own = kt; ip_own = invP; }
            const double Lm = (diag_r > -1.0e307 && tid != kt) ? col * invP : 0.0;
            const double fyk = __shfl(fy_r, kt, 64);
            fy_r -= Lm * fyk;                       // unit-L forward solve
            #pragma unroll
            for (int j = 0; j < MEQ; ++j) {         // guarded rank-1 update
                const double urj = __shfl(Sreg[j], kt, 64);   // pivot row
                const bool live = ((elimMask >> j) & 1ull) == 0ull;
                double nv = live ? (Sreg[j] - Lm * urj) : Sreg[j];
                if (j == kt) nv = Lm;               // stash multiplier in-place
                Sreg[j] = nv;
            }
            diag_r -= Lm * col;                     // selector maintenance
            if (tid == kt) diag_r = -1.0e308;       // eliminated
            elimMask |= (1ull << kt);
        }

        // ---- P4: backward solve x_t = fy_t*invP_t - sum_i L[i][t] * X_i ----
        double X_r = 0.0;                           // dy at owner lanes
        for (int t = MEQ - 1; t >= 0; --t) {
            const int kt = __builtin_amdgcn_readfirstlane(__shfl(kk_own, t, 64));
            // Lm_t per lane = stored multiplier in column kt
            double Lm = Sreg[0];
            #pragma unroll
            for (int j = 1; j < MEQ; ++j) if (j == kt) Lm = Sreg[j];
            double ssum = Lm * X_r;
            for (int off = 32; off; off >>= 1) ssum += __shfl_xor(ssum, off, 64);
            const double ipt = __shfl(ip_own, t, 64);
            const double fyk = __shfl(fy_r, kt, 64);
            double xt = fyk * ipt - ssum;
            xt = (ipt != 0.0) ? xt : 0.0;           // dropped direction -> 0
            if (tid == kt) X_r = xt;
        }

        // ---- P5: dx/ds/dz, ratio test, updates ----
        double atdy = 0.0;
        #pragma unroll 4
        for (int j = 0; j < MEQ; ++j) atdy += Ald[j * SA + tid] * __shfl(X_r, j, 64);
        const double dx = d_r * (rx - atdy);
        const double ds = dx - rs;                   // -rs + dx
        const double dz = rc - (z_r / s_r) * dx;
        double r = 1.0e300;
        if (ds < 0.0) r = -s_r / ds;
        if (dz < 0.0) r = fmin(r, -z_r / dz);
        for (int off = 32; off; off >>= 1) r = fmin(r, __shfl_xor(r, off, 64));
        const double alpha = fmin(1.0, FTB_C * r);
        x_r += alpha * dx;
        s_r += alpha * ds;
        z_r += alpha * dz;
        y_r += alpha * X_r;                          // X_r==0 for lanes>=40
    }

    out[b * NXV + tid] = (float)x_r;
}

extern "C" void kernel_launch(void* const* d_in, const int* in_sizes, int n_in,
                              void* d_out, int out_size, void* d_ws, size_t ws_size,
                              hipStream_t stream) {
    const float* puzzles = (const float*)d_in[0];
    const float* A       = (const float*)d_in[1];   // declared f64, delivered f32
    const float* logz0   = (const float*)d_in[2];
    // d_in[3] = Q (zeros, structural), d_in[4] = G (-I, structural)
    const float* u       = (const float*)d_in[5];
    float* out = (float*)d_out;

    const int n_batch = in_sizes[0] / NXV;   // 1024
    qp_ipm_kernel<<<n_batch, 64, 0, stream>>>(puzzles, A, logz0, u, out);
}

// Round 15
// 2315.286 us; speedup vs baseline: 1.5279x; 1.5279x over previous
//
#include <hip/hip_runtime.h>
#include <math.h>

// QPLayer: batched primal-dual IPM, Q=0, G=-I (LP). f64 inputs DELIVERED AS F32
// (established round 8). Schur complement S = A diag(s/z) A^T (40x40), solved
// with COMPLETE-DIAGONAL-PIVOTED LDL^T (greedy max pivot), register-resident
// trailing matrix (lane i owns row i).
// ROUND 15: multipliers live in the DEAD Sl LDS buffer (free after the
// register load until next iteration's P2): P3 writes Lm -> Sl[t*40+tid]
// (one ds_write_b64/step), P4 reads it back (one ds_read_b64/step).
// This kills round 14's elimMask guards (~8k VALU ops/iter) and P4 select
// chain (~3.2k ops/iter) AND round 13's Lmh register array (which spilled to
// scratch: 381 MB/dispatch). Unguarded rank-1 update == round 13 semantics
// (eliminated columns hold garbage, never read). t-loops rolled (I-cache);
// inner j-loops unrolled for static Sreg indexing. 3 barriers/iter.
// One wave per batch element; 1024 waves = 4/CU (structural).

#define NXV   64
#define MEQ   40
#define NITER 25
#define SIGMA_C 0.1
#define FTB_C   0.99
#define SA 65    // LDS row stride for A (doubles)
#define SS 41    // LDS row stride for S staging (doubles); Sl reused for Lm
#define PIV_DROP_REL 1e-12

__global__ __launch_bounds__(64, 1)
void qp_ipm_kernel(const float* __restrict__ puzzles,
                   const float* __restrict__ Af,
                   const float* __restrict__ lzf,
                   const float* __restrict__ uf,
                   float* __restrict__ out)
{
    __shared__ double Ald[MEQ * SA];   // 20,800 B
    __shared__ double Sl[MEQ * SS];    // 13,120 B (S staging, then Lm store)
    __shared__ double dl[NXV];         //    512 B

    const int tid = threadIdx.x;       // 0..63, one wave
    const int b   = blockIdx.x;
    const int row = (tid < MEQ) ? tid : 0;

    // ---- setup: A (f32->f64) into LDS; b_r = (A @ exp(log_z0))_row ----
    for (int e = tid; e < MEQ * NXV; e += 64)
        Ald[(e >> 6) * SA + (e & 63)] = (double)Af[e];
    const double ez = exp((double)lzf[tid]);
    __syncthreads();
    double b_r = 0.0;
    #pragma unroll 4
    for (int i = 0; i < NXV; ++i) b_r += Ald[row * SA + i] * __shfl(ez, i, 64);

    const double u_i = (double)uf[tid];
    const double p_i = -(double)puzzles[b * NXV + tid];
    double x_r = 0.0, s_r = 1.0, z_r = 1.0, y_r = 0.0;

    for (int it = 0; it < NITER; ++it) {
        // ---- P1: residuals/scalings, registers (uniform flow) ----
        double aty = 0.0;
        #pragma unroll 4
        for (int j = 0; j < MEQ; ++j) aty += Ald[j * SA + tid] * __shfl(y_r, j, 64);
        const double rd = p_i + aty - z_r;          // Q=0, G^T z = -z
        const double rs = s_r - x_r - u_i;          // -x + s - u
        double m = s_r * z_r;
        for (int off = 32; off; off >>= 1) m += __shfl_xor(m, off, 64);
        const double mu = m * (1.0 / 64.0);
        const double rc = (SIGMA_C * mu - z_r * s_r + z_r * rs) / s_r;
        const double rx = rc - rd;                  // rhs_x
        const double d_r = s_r / z_r;
        const double v_r = d_r * rx + x_r;          // fy = A v - b

        double fy_r = 0.0;                          // rhs_y at lane row
        #pragma unroll 4
        for (int i = 0; i < NXV; ++i) fy_r += Ald[row * SA + i] * __shfl(v_r, i, 64);
        fy_r -= b_r;

        dl[tid] = d_r;                              // stage d (all 64 lanes)
        __syncthreads();                            // barrier 0: dl visible

        // ---- P2: S = A diag(d) A^T, 4x4 lower tiles (lanes<55) -> LDS ----
        if (tid < 55) {
            int uu = tid, mb = 0;
            while (uu > mb) { uu -= (mb + 1); ++mb; }
            const int nb = uu;
            double a00=0,a01=0,a02=0,a03=0, a10=0,a11=0,a12=0,a13=0,
                   a20=0,a21=0,a22=0,a23=0, a30=0,a31=0,a32=0,a33=0;
            const double* Am = &Ald[(4 * mb) * SA];
            const double* An = &Ald[(4 * nb) * SA];
            for (int k = 0; k < NXV; ++k) {
                const double dk = dl[k];
                const double r0 = Am[0*SA+k], r1 = Am[1*SA+k], r2 = Am[2*SA+k], r3 = Am[3*SA+k];
                const double c0 = An[0*SA+k]*dk, c1 = An[1*SA+k]*dk, c2 = An[2*SA+k]*dk, c3 = An[3*SA+k]*dk;
                a00 += r0*c0; a01 += r0*c1; a02 += r0*c2; a03 += r0*c3;
                a10 += r1*c0; a11 += r1*c1; a12 += r1*c2; a13 += r1*c3;
                a20 += r2*c0; a21 += r2*c1; a22 += r2*c2; a23 += r2*c3;
                a30 += r3*c0; a31 += r3*c1; a32 += r3*c2; a33 += r3*c3;
            }
            double* Sp = &Sl[(4 * mb) * SS + 4 * nb];
            Sp[0*SS+0]=a00; Sp[0*SS+1]=a01; Sp[0*SS+2]=a02; Sp[0*SS+3]=a03;
            Sp[1*SS+0]=a10; Sp[1*SS+1]=a11; Sp[1*SS+2]=a12; Sp[1*SS+3]=a13;
            Sp[2*SS+0]=a20; Sp[2*SS+1]=a21; Sp[2*SS+2]=a22; Sp[2*SS+3]=a23;
            Sp[3*SS+0]=a30; Sp[3*SS+1]=a31; Sp[3*SS+2]=a32; Sp[3*SS+3]=a33;
        }
        __syncthreads();   // barrier 1: tiles visible

        // ---- load row tid of S into registers (symmetric fill) ----
        double Sreg[MEQ];
        double diag_r;
        if (tid < MEQ) {
            #pragma unroll
            for (int j = 0; j < MEQ; ++j)
                Sreg[j] = (j <= tid) ? Sl[tid * SS + j] : Sl[j * SS + tid];
            diag_r = Sl[tid * SS + tid];
        } else {
            #pragma unroll
            for (int j = 0; j < MEQ; ++j) Sreg[j] = 0.0;
            diag_r = -1.0e308;
        }
        double dg = diag_r;
        for (int off = 32; off; off >>= 1) dg = fmax(dg, __shfl_xor(dg, off, 64));
        const double thr = dg * PIV_DROP_REL;
        __syncthreads();   // barrier 2: Sl now dead -> reuse as Lm store

        // ---- P3: greedy-max-pivot LDL^T; Lm spilled to Sl (LDS, not scratch) ----
        double ip_own = 0.0;
        int    kk_own = 0;
        for (int t = 0; t < MEQ; ++t) {
            // argmax over remaining diagonal (selector butterfly)
            double v = diag_r; int idx = tid;
            for (int off = 32; off; off >>= 1) {
                const double ov = __shfl_xor(v, off, 64);
                const int    oi = __shfl_xor(idx, off, 64);
                if (ov > v || (ov == v && oi < idx)) { v = ov; idx = oi; }
            }
            const int kt = __builtin_amdgcn_readfirstlane(idx);
            // col_i = S[i][kt] — static-index select chain (uniform kt)
            double col = Sreg[0];
            #pragma unroll
            for (int j = 1; j < MEQ; ++j) if (j == kt) col = Sreg[j];
            const double piv  = __shfl(col, kt, 64);         // stored-copy pivot
            const double invP = (piv > thr) ? (1.0 / piv) : 0.0;
            if (tid == t) { kk_own = kt; ip_own = invP; }
            const double Lm = (diag_r > -1.0e307 && tid != kt) ? col * invP : 0.0;
            if (tid < MEQ) Sl[t * MEQ + tid] = Lm;   // multiplier -> dead LDS
            const double fyk = __shfl(fy_r, kt, 64);
            fy_r -= Lm * fyk;                        // unit-L forward solve
            #pragma unroll
            for (int j = 0; j < MEQ; ++j) {          // unguarded rank-1 update
                const double urj = __shfl(Sreg[j], kt, 64);   // pivot row
                Sreg[j] -= Lm * urj;
            }
            diag_r -= Lm * col;                      // selector maintenance
            if (tid == kt) diag_r = -1.0e308;        // eliminated
        }

        // ---- P4: backward solve x_t = fy_t*invP_t - sum_i Lm[t][i] * X_i ----
        double X_r = 0.0;                            // dy at owner lanes
        for (int t = MEQ - 1; t >= 0; --t) {
            const double Lm = (tid < MEQ) ? Sl[t * MEQ + tid] : 0.0;
            double ssum = Lm * X_r;
            for (int off = 32; off; off >>= 1) ssum += __shfl_xor(ssum, off, 64);
            const int    kt  = __builtin_amdgcn_readfirstlane(__shfl(kk_own, t, 64));
            const double ipt = __shfl(ip_own, t, 64);
            const double fyk = __shfl(fy_r, kt, 64);
            double xt = fyk * ipt - ssum;
            xt = (ipt != 0.0) ? xt : 0.0;            // dropped direction -> 0
            if (tid == kt) X_r = xt;
        }

        // ---- P5: dx/ds/dz, ratio test, updates ----
        double atdy = 0.0;
        #pragma unroll 4
        for (int j = 0; j < MEQ; ++j) atdy += Ald[j * SA + tid] * __shfl(X_r, j, 64);
        const double dx = d_r * (rx - atdy);
        const double ds = dx - rs;                   // -rs + dx
        const double dz = rc - (z_r / s_r) * dx;
        double r = 1.0e300;
        if (ds < 0.0) r = -s_r / ds;
        if (dz < 0.0) r = fmin(r, -z_r / dz);
        for (int off = 32; off; off >>= 1) r = fmin(r, __shfl_xor(r, off, 64));
        const double alpha = fmin(1.0, FTB_C * r);
        x_r += alpha * dx;
        s_r += alpha * ds;
        z_r += alpha * dz;
        y_r += alpha * X_r;                          // X_r==0 for lanes>=40
        __syncthreads();                             // Sl(Lm) dead before next P2
    }

    out[b * NXV + tid] = (float)x_r;
}

extern "C" void kernel_launch(void* const* d_in, const int* in_sizes, int n_in,
                              void* d_out, int out_size, void* d_ws, size_t ws_size,
                              hipStream_t stream) {
    const float* puzzles = (const float*)d_in[0];
    const float* A       = (const float*)d_in[1];   // declared f64, delivered f32
    const float* logz0   = (const float*)d_in[2];
    // d_in[3] = Q (zeros, structural), d_in[4] = G (-I, structural)
    const float* u       = (const float*)d_in[5];
    float* out = (float*)d_out;

    const int n_batch = in_sizes[0] / NXV;   // 1024
    qp_ipm_kernel<<<n_batch, 64, 0, stream>>>(puzzles, A, logz0, u, out);
}